// Round 7
// baseline (237.198 us; speedup 1.0000x reference)
//
#include <hip/hip_runtime.h>

#define D_MODEL   2048
#define N_EXPERTS 64
#define THRESH    0.9f
#define TOK_BLK   32   // tokens per block (2 tiles of 16)
#define NWAVES    8    // waves per block: wave = (tile<<2) | kv
#define KSPLIT    4    // K-split across 4 waves

typedef __attribute__((ext_vector_type(8))) short bf16x8;
typedef __attribute__((ext_vector_type(4))) float f32x4;

union FragU { unsigned u[4]; bf16x8 v; };

__device__ __forceinline__ unsigned pack_hi(float f0, float f1) {
    return __builtin_amdgcn_perm(__float_as_uint(f1), __float_as_uint(f0), 0x07060302u);
}
__device__ __forceinline__ float trunc_bf(float f) {
    return __uint_as_float(__float_as_uint(f) & 0xFFFF0000u);
}

// ---- prepack W [2048][64] fp32 -> EXACT 3-way bf16 split fragments in d_ws
__global__ void prepack_w(const float* __restrict__ W,
                          bf16x8* __restrict__ c0, bf16x8* __restrict__ c1,
                          bf16x8* __restrict__ c2)
{
    const int ks = blockIdx.x;
    const int nt = threadIdx.x >> 6;
    const int l  = threadIdx.x & 63;
    const int col  = nt * 16 + (l & 15);
    const int krow = ks * 32 + ((l >> 4) << 3);
    FragU F0, F1, F2;
#pragma unroll
    for (int j = 0; j < 4; ++j) {
        const float a = W[(size_t)(krow + 2*j    ) * N_EXPERTS + col];
        const float b = W[(size_t)(krow + 2*j + 1) * N_EXPERTS + col];
        const float ra = a - trunc_bf(a),  rb = b - trunc_bf(b);
        const float sa = ra - trunc_bf(ra), sb = rb - trunc_bf(rb);
        F0.u[j] = pack_hi(a,  b);
        F1.u[j] = pack_hi(ra, rb);
        F2.u[j] = pack_hi(sa, sb);   // exact: a = F0+F1+F2
    }
    const int idx = (ks * 4 + nt) * 64 + l;
    c0[idx] = F0.v; c1[idx] = F1.v; c2[idx] = F2.v;
}

// ---- main: 32 tokens/block, 8 waves = 2 tiles x 4-way K-split,
//      16 k-steps/wave (deep ILP), 6-term MFMA, LDS reduce, epilogue
__global__ __launch_bounds__(512, 6)
void dynk_mfma(const float* __restrict__ x,
               const bf16x8* __restrict__ c0, const bf16x8* __restrict__ c1,
               const bf16x8* __restrict__ c2,
               const float* __restrict__ b,
               float* __restrict__ out_rw, float* __restrict__ out_probs,
               float* __restrict__ out_cnt, int n_tok)
{
    __shared__ float red[NWAVES * 16 * 64];     // 32 KB: [tile*4+kv][row][expert]
    const int l  = threadIdx.x & 63;
    const int w  = threadIdx.x >> 6;            // 0..7
    const int t  = w >> 2;                      // token tile 0..1
    const int kv = w & 3;                       // K quarter
    const int tok0 = blockIdx.x * TOK_BLK;

    const int r = l & 15;                       // A row / B col within tile
    const int q = l >> 4;                       // k sub-block
    int xr = tok0 + t * 16 + r; if (xr >= n_tok) xr = n_tok - 1;
    // wave's K range starts at element kv*512; lane offset q*8
    const float* xrow = x + (size_t)xr * D_MODEL + kv * 512 + q * 8;

    // B fragment base for this wave's K quarter: element offset (kv*16*4)*64 + l
    const size_t bbase = (size_t)(kv * 16 * 4) * 64 + l;
    const bf16x8* B0p = c0 + bbase;
    const bf16x8* B1p = c1 + bbase;
    const bf16x8* B2p = c2 + bbase;

    f32x4 acc[4] = {f32x4{0,0,0,0}, f32x4{0,0,0,0}, f32x4{0,0,0,0}, f32x4{0,0,0,0}};

#pragma unroll 4
    for (int s = 0; s < 16; ++s) {
        const float4 xa = *reinterpret_cast<const float4*>(xrow + s * 32);
        const float4 xb = *reinterpret_cast<const float4*>(xrow + s * 32 + 4);
        const float f[8] = {xa.x, xa.y, xa.z, xa.w, xb.x, xb.y, xb.z, xb.w};

        FragU A0, A1, A2;
#pragma unroll
        for (int j = 0; j < 4; ++j) {
            const float p0 = f[2*j], p1 = f[2*j+1];
            const float r0 = p0 - trunc_bf(p0), r1 = p1 - trunc_bf(p1);
            const float s0 = r0 - trunc_bf(r0), s1 = r1 - trunc_bf(r1);
            A0.u[j] = pack_hi(p0, p1);
            A1.u[j] = pack_hi(r0, r1);
            A2.u[j] = pack_hi(s0, s1);
        }

#pragma unroll
        for (int nt = 0; nt < 4; ++nt) {
            const int off = s * 256 + nt * 64;
            const bf16x8 B0 = B0p[off];
            const bf16x8 B1 = B1p[off];
            const bf16x8 B2 = B2p[off];
            acc[nt] = __builtin_amdgcn_mfma_f32_16x16x32_bf16(A2.v, B0, acc[nt], 0, 0, 0);
            acc[nt] = __builtin_amdgcn_mfma_f32_16x16x32_bf16(A0.v, B2, acc[nt], 0, 0, 0);
            acc[nt] = __builtin_amdgcn_mfma_f32_16x16x32_bf16(A1.v, B1, acc[nt], 0, 0, 0);
            acc[nt] = __builtin_amdgcn_mfma_f32_16x16x32_bf16(A1.v, B0, acc[nt], 0, 0, 0);
            acc[nt] = __builtin_amdgcn_mfma_f32_16x16x32_bf16(A0.v, B1, acc[nt], 0, 0, 0);
            acc[nt] = __builtin_amdgcn_mfma_f32_16x16x32_bf16(A0.v, B0, acc[nt], 0, 0, 0);
        }
    }

    // D layout: col=lane&15, row=(lane>>4)*4+j  (verified rounds 3/4/6)
#pragma unroll
    for (int nt = 0; nt < 4; ++nt)
#pragma unroll
        for (int j = 0; j < 4; ++j)
            red[(w * 16 + q * 4 + j) * 64 + (nt * 16 + r)] = acc[nt][j];
    __syncthreads();

    // epilogue: wave w owns tokens w*4 .. w*4+3; lane = expert
#pragma unroll 1
    for (int e = 0; e < 4; ++e) {
        const int tt  = w * 4 + e;              // 0..31
        const int t2  = tt >> 4;
        const int row = tt & 15;
        const long tok = (long)tok0 + tt;
        if (tok >= n_tok) break;

        float lg = b[l];
#pragma unroll
        for (int k2 = 0; k2 < KSPLIT; ++k2)
            lg += red[((t2 * 4 + k2) * 16 + row) * 64 + l];

        float m = lg;
#pragma unroll
        for (int d = 32; d > 0; d >>= 1) m = fmaxf(m, __shfl_xor(m, d));
        const float e0 = expf(lg - m);
        float sden = e0;
#pragma unroll
        for (int d = 32; d > 0; d >>= 1) sden += __shfl_xor(sden, d);
        const float p = e0 / sden;

        // mass of experts ranked strictly before this lane (stable ties by index)
        float S = 0.f;
#pragma unroll
        for (int j = 0; j < 64; ++j) {
            const float pj = __shfl(p, j);
            const bool before = (pj > p) || (pj == p && j < l);
            S += before ? pj : 0.f;
        }
        const bool active = (S < THRESH);

        float total = active ? p : 0.f;
#pragma unroll
        for (int d = 32; d > 0; d >>= 1) total += __shfl_xor(total, d);

        const int cnt = __popcll(__ballot(active));
        const float wgt = active ? p / (total + 1e-6f) : 0.f;

        out_rw[tok * N_EXPERTS + l]    = wgt;
        out_probs[tok * N_EXPERTS + l] = p;
        if (l == 0) out_cnt[tok] = (float)cnt;
    }
}

// ---- fallback (round-2 proven fp32 kernel) if workspace is too small
__global__ __launch_bounds__(256, 2)
void dynk_fallback(const float* __restrict__ x, const float* __restrict__ W,
                   const float* __restrict__ b, float* __restrict__ out_rw,
                   float* __restrict__ out_probs, float* __restrict__ out_cnt,
                   int n_tok)
{
    const int lane = threadIdx.x & 63;
    const int wid  = threadIdx.x >> 6;
    const long tok0 = (long)blockIdx.x * 32 + (long)wid * 8;
    if (tok0 >= n_tok) return;
    float acc[8];
    const float bias = b[lane];
#pragma unroll
    for (int t = 0; t < 8; ++t) acc[t] = bias;
    const float* xp = x + tok0 * D_MODEL;
    for (int k0 = 0; k0 < D_MODEL; k0 += 8) {
        float w[8];
#pragma unroll
        for (int j = 0; j < 8; ++j) w[j] = W[(long)(k0 + j) * N_EXPERTS + lane];
#pragma unroll
        for (int t = 0; t < 8; ++t) {
            const float4 xa = *reinterpret_cast<const float4*>(xp + (long)t * D_MODEL + k0);
            const float4 xb = *reinterpret_cast<const float4*>(xp + (long)t * D_MODEL + k0 + 4);
            acc[t] = fmaf(xa.x, w[0], acc[t]); acc[t] = fmaf(xa.y, w[1], acc[t]);
            acc[t] = fmaf(xa.z, w[2], acc[t]); acc[t] = fmaf(xa.w, w[3], acc[t]);
            acc[t] = fmaf(xb.x, w[4], acc[t]); acc[t] = fmaf(xb.y, w[5], acc[t]);
            acc[t] = fmaf(xb.z, w[6], acc[t]); acc[t] = fmaf(xb.w, w[7], acc[t]);
        }
    }
#pragma unroll 1
    for (int t = 0; t < 8; ++t) {
        const long tok = tok0 + t;
        const float lgt = acc[t];
        float m = lgt;
#pragma unroll
        for (int d = 32; d > 0; d >>= 1) m = fmaxf(m, __shfl_xor(m, d));
        const float e = expf(lgt - m);
        float s = e;
#pragma unroll
        for (int d = 32; d > 0; d >>= 1) s += __shfl_xor(s, d);
        const float p = e / s;
        float S = 0.f;
#pragma unroll
        for (int j = 0; j < 64; ++j) {
            const float pj = __shfl(p, j);
            S += ((pj > p) || (pj == p && j < lane)) ? pj : 0.f;
        }
        const bool active = (S < THRESH);
        float total = active ? p : 0.f;
#pragma unroll
        for (int d = 32; d > 0; d >>= 1) total += __shfl_xor(total, d);
        const int cnt = __popcll(__ballot(active));
        const float wgt = active ? p / (total + 1e-6f) : 0.f;
        out_rw[tok * N_EXPERTS + lane]    = wgt;
        out_probs[tok * N_EXPERTS + lane] = p;
        if (lane == 0) out_cnt[tok] = (float)cnt;
    }
}

extern "C" void kernel_launch(void* const* d_in, const int* in_sizes, int n_in,
                              void* d_out, int out_size, void* d_ws, size_t ws_size,
                              hipStream_t stream) {
    const float* x = (const float*)d_in[0];
    const float* W = (const float*)d_in[1];
    const float* b = (const float*)d_in[2];
    const int n_tok = in_sizes[0] / D_MODEL;

    float* out   = (float*)d_out;
    float* rw    = out;
    float* probs = out + (size_t)n_tok * N_EXPERTS;
    float* cnt   = out + 2 * (size_t)n_tok * N_EXPERTS;

    const size_t frag_elems = 64 * 4 * 64;                // per split level
    const size_t need = 3 * frag_elems * sizeof(bf16x8);  // 768 KB

    if (ws_size < need) {
        const int blocks = (n_tok + 31) / 32;
        dynk_fallback<<<blocks, 256, 0, stream>>>(x, W, b, rw, probs, cnt, n_tok);
        return;
    }

    bf16x8* c0 = (bf16x8*)d_ws;
    bf16x8* c1 = c0 + frag_elems;
    bf16x8* c2 = c1 + frag_elems;

    prepack_w<<<64, 256, 0, stream>>>(W, c0, c1, c2);

    const int blocks = (n_tok + TOK_BLK - 1) / TOK_BLK;
    dynk_mfma<<<blocks, 512, 0, stream>>>(x, c0, c1, c2, b, rw, probs, cnt, n_tok);
}